// Round 12
// baseline (452.861 us; speedup 1.0000x reference)
//
#include <hip/hip_runtime.h>
#include <stdint.h>

// Problem constants (from reference): T=128, K=8, H=2048, E=64, I=768
constexpr int Tn = 128;
constexpr int Kn = 8;
constexpr int Hn = 2048;
constexpr int En = 64;
constexpr int In = 768;
constexpr int NP = Tn * Kn;      // 1024 pairs
constexpr int NTI = In / 128;    // 6 col tiles of 128 (gateup)

// ---------------- routing: build CSR of pair-ids per expert ----------------
__global__ void route_kernel(const int* __restrict__ idx32,
                             int* __restrict__ offsets,   // E+1 ints (512 B slot)
                             int* __restrict__ entries) { // NP pair ids
  __shared__ int s_cnt[En];
  __shared__ int s_cur[En];
  __shared__ int s_odd_or;
  const int tid = threadIdx.x;
  if (tid == 0) s_odd_or = 0;
  if (tid < En) s_cnt[tid] = 0;
  __syncthreads();
  if (tid < NP / 2) {
    if (idx32[2 * tid + 1] != 0) atomicOr(&s_odd_or, 1);
  }
  __syncthreads();
  const bool is64 = (s_odd_or == 0);
  const int e = is64 ? idx32[2 * tid] : idx32[tid];
  atomicAdd(&s_cnt[e], 1);
  __syncthreads();
  if (tid == 0) {
    int acc = 0;
    for (int i = 0; i < En; ++i) { s_cur[i] = acc; offsets[i] = acc; acc += s_cnt[i]; }
    offsets[En] = acc;
  }
  __syncthreads();
  const int pos = atomicAdd(&s_cur[e], 1);
  entries[pos] = tid;  // pair id = t*K + k
}

// ------------- phase A: exact down_kernel geometry, full-H reduction -------
// grid = 2 * E * NTI = 768; block 256 = 4 waves, 8 rows/wave (static).
// One weight stream (wg or wu) per block; full H per block -> plain stores.
// gu layout [2][NP][In] fp32, CSR-position-indexed (no memset needed).
__global__ __launch_bounds__(256, 2) void gateup_mono(
    const float* __restrict__ hs, const float* __restrict__ wg,
    const float* __restrict__ wu, const int* __restrict__ offsets,
    const int* __restrict__ entries, float* __restrict__ gu) {
  const int b = blockIdx.x;
  const int tile = b % NTI;
  const int em = b / NTI;            // 0..127
  const int e = em & 63;
  const int m = em >> 6;             // 0 = gate, 1 = up
  const int beg = offsets[e];
  const int cnt = offsets[e + 1] - beg;
  if (cnt == 0) return;

  const int wave = threadIdx.x >> 6;
  const int lane = threadIdx.x & 63;
  const int col = tile * 128 + lane * 2;

  __shared__ float s_h[32][64];
  __shared__ int s_tok[32];

  const float* W = m ? wu : wg;
  const float* wp = W + (size_t)e * Hn * In + col;
  float* gup = gu + (size_t)m * NP * In;

  for (int chunk = 0; chunk < cnt; chunk += 32) {
    __syncthreads();
    if (threadIdx.x < 32) {
      const int r = threadIdx.x;
      s_tok[r] = entries[beg + chunk + min(r, cnt - chunk - 1)] >> 3;  // clamp
    }
    __syncthreads();

    float2 acc[8];
#pragma unroll
    for (int j = 0; j < 8; ++j) acc[j] = make_float2(0.f, 0.f);

    for (int d0 = 0; d0 < Hn; d0 += 64) {
      {  // stage h[rows, d0:d0+64] -> LDS (32 rows x 64 floats)
        const int r = threadIdx.x >> 3;
        const int g = (threadIdx.x & 7) * 8;
        const float* src = hs + (size_t)s_tok[r] * Hn + d0 + g;
        const float4 a = *reinterpret_cast<const float4*>(src);
        const float4 b4 = *reinterpret_cast<const float4*>(src + 4);
        *reinterpret_cast<float4*>(&s_h[r][g]) = a;
        *reinterpret_cast<float4*>(&s_h[r][g + 4]) = b4;
      }
      __syncthreads();
      const float* wdd = wp + (size_t)d0 * In;
#pragma unroll 2
      for (int dg = 0; dg < 64; dg += 4) {
        float2 wv[4];
#pragma unroll
        for (int q = 0; q < 4; ++q)
          wv[q] = *reinterpret_cast<const float2*>(wdd + (size_t)(dg + q) * In);
#pragma unroll
        for (int j = 0; j < 8; ++j) {
          const float4 hv = *reinterpret_cast<const float4*>(&s_h[wave * 8 + j][dg]);
          const float hvv[4] = {hv.x, hv.y, hv.z, hv.w};
#pragma unroll
          for (int q = 0; q < 4; ++q) {
            acc[j].x = fmaf(hvv[q], wv[q].x, acc[j].x);
            acc[j].y = fmaf(hvv[q], wv[q].y, acc[j].y);
          }
        }
      }
      __syncthreads();
    }

#pragma unroll
    for (int j = 0; j < 8; ++j) {
      const int r = wave * 8 + j;
      if (chunk + r < cnt) {  // full-H per block: plain store, no atomics
        *reinterpret_cast<float2*>(&gup[(size_t)(beg + chunk + r) * In + col]) =
            acc[j];
      }
    }
  }
}

// ------------- silu combine: act = silu(gate)*up, in place over gate -------
__global__ void silu_kernel(float* __restrict__ gu) {
  const int i = blockIdx.x * blockDim.x + threadIdx.x;  // over NP*In/4 float4
  float4* g4 = reinterpret_cast<float4*>(gu);
  const float4* u4 = reinterpret_cast<const float4*>(gu + (size_t)NP * In);
  float4 g = g4[i];
  const float4 u = u4[i];
  g.x = g.x / (1.f + __expf(-g.x)) * u.x;
  g.y = g.y / (1.f + __expf(-g.y)) * u.y;
  g.z = g.z / (1.f + __expf(-g.z)) * u.z;
  g.w = g.w / (1.f + __expf(-g.w)) * u.w;
  g4[i] = g;
}

// ---------------- phase B: out[t] += w * act @ Wd (proven R5 form) ---------
// grid = E * (H/128) = 1024; block 256.
__global__ __launch_bounds__(256, 2) void down_kernel(
    const float* __restrict__ act, const float* __restrict__ wd,
    const float* __restrict__ tkw, const int* __restrict__ offsets,
    const int* __restrict__ entries, float* __restrict__ out) {
  const int e = blockIdx.x >> 4;     // H/128 = 16 tiles
  const int tile = blockIdx.x & 15;
  const int beg = offsets[e];
  const int cnt = offsets[e + 1] - beg;
  if (cnt == 0) return;

  const int wave = threadIdx.x >> 6;
  const int lane = threadIdx.x & 63;
  const int col = tile * 128 + lane * 2;

  __shared__ float s_a[32][64];
  __shared__ int s_tok[32];
  __shared__ int s_arow[32];
  __shared__ float s_w[32];

  const float* wdp = wd + (size_t)e * In * Hn + col;

  for (int chunk = 0; chunk < cnt; chunk += 32) {
    __syncthreads();
    if (threadIdx.x < 32) {
      const int r = threadIdx.x;
      const int rr = min(r, cnt - chunk - 1);
      const int p = entries[beg + chunk + rr];
      s_tok[r] = p >> 3;
      s_w[r] = tkw[p];
      s_arow[r] = beg + chunk + rr;  // CSR position
    }
    __syncthreads();

    float2 acc[8];
#pragma unroll
    for (int j = 0; j < 8; ++j) acc[j] = make_float2(0.f, 0.f);

    for (int i0 = 0; i0 < In; i0 += 64) {
      {
        const int r = threadIdx.x >> 3;
        const int g = (threadIdx.x & 7) * 8;
        const float* src = act + (size_t)s_arow[r] * In + i0 + g;
        const float4 a = *reinterpret_cast<const float4*>(src);
        const float4 b4 = *reinterpret_cast<const float4*>(src + 4);
        *reinterpret_cast<float4*>(&s_a[r][g]) = a;
        *reinterpret_cast<float4*>(&s_a[r][g + 4]) = b4;
      }
      __syncthreads();
      const float* wdi = wdp + (size_t)i0 * Hn;
#pragma unroll 2
      for (int ig = 0; ig < 64; ig += 4) {
        float2 wdv[4];
#pragma unroll
        for (int q = 0; q < 4; ++q)
          wdv[q] = *reinterpret_cast<const float2*>(wdi + (size_t)(ig + q) * Hn);
#pragma unroll
        for (int j = 0; j < 8; ++j) {
          const float4 av = *reinterpret_cast<const float4*>(&s_a[wave * 8 + j][ig]);
          const float avv[4] = {av.x, av.y, av.z, av.w};
#pragma unroll
          for (int q = 0; q < 4; ++q) {
            acc[j].x = fmaf(avv[q], wdv[q].x, acc[j].x);
            acc[j].y = fmaf(avv[q], wdv[q].y, acc[j].y);
          }
        }
      }
      __syncthreads();
    }

#pragma unroll
    for (int j = 0; j < 8; ++j) {
      const int r = wave * 8 + j;
      if (chunk + r < cnt) {
        const float w = s_w[r];
        float* op = out + (size_t)s_tok[r] * Hn + col;
        atomicAdd(op, w * acc[j].x);
        atomicAdd(op + 1, w * acc[j].y);
      }
    }
  }
}

extern "C" void kernel_launch(void* const* d_in, const int* in_sizes, int n_in,
                              void* d_out, int out_size, void* d_ws, size_t ws_size,
                              hipStream_t stream) {
  const float* hs  = (const float*)d_in[0];
  const int*   idx = (const int*)d_in[1];
  const float* tkw = (const float*)d_in[2];
  const float* wg  = (const float*)d_in[3];
  const float* wu  = (const float*)d_in[4];
  const float* wd  = (const float*)d_in[5];
  float* out = (float*)d_out;

  // Workspace: [0,512) offsets | [512,4608) entries | [8192,..) gu[2][NP][In]
  char* ws = (char*)d_ws;
  int* offsets = (int*)ws;
  int* entries = (int*)(ws + 512);
  float* gu    = (float*)(ws + 8192);

  route_kernel<<<1, NP, 0, stream>>>(idx, offsets, entries);
  hipMemsetAsync(d_out, 0, (size_t)Tn * Hn * sizeof(float), stream);
  gateup_mono<<<2 * En * NTI, 256, 0, stream>>>(hs, wg, wu, offsets, entries, gu);
  silu_kernel<<<NP * In / 4 / 256, 256, 0, stream>>>(gu);
  down_kernel<<<En * (Hn / 128), 256, 0, stream>>>(gu, wd, tkw, offsets, entries, out);
}